// Round 1
// 1558.768 us; speedup vs baseline: 1.1042x; 1.1042x over previous
//
#include <hip/hip_runtime.h>
#include <cstdint>
#include <cstddef>

#define BATCH    16384
#define INF      5000
#define KPAD_IN  5024      // 157*32
#define N0       512
#define N1       512
#define N2       256
#define NUM_T    16
#define XK       288       // 257 padded to 9*32
#define N3       10000
#define N3PAD    10112     // 79*128

typedef _Float16 f16;
typedef _Float16 f16x8 __attribute__((ext_vector_type(8)));
typedef float    f32x4 __attribute__((ext_vector_type(4)));

typedef __attribute__((address_space(1))) void gvoid;
typedef __attribute__((address_space(3))) void lvoid;

__device__ __forceinline__ void gload_lds16(const void* g, void* l) {
    // async global->LDS, 16B/lane; LDS dest = wave-uniform base + lane*16
    __builtin_amdgcn_global_load_lds((gvoid*)g, (lvoid*)l, 16, 0, 0);
}

// hardware transcendentals: v_exp_f32 = 2^x, v_log_f32 = log2(x)
__device__ __forceinline__ float fast_exp2(float x) {
    float r; asm("v_exp_f32 %0, %1" : "=v"(r) : "v"(x)); return r;
}
__device__ __forceinline__ float fast_log2(float x) {
    float r; asm("v_log_f32 %0, %1" : "=v"(r) : "v"(x)); return r;
}
// softplus(v) = max(v,0) + ln2*log2(1 + 2^(-|v|*log2e)); stable, ~9 VALU ops
__device__ __forceinline__ float fast_softplus(float v) {
    float t = fast_exp2(-fabsf(v) * 1.44269504f);      // e^{-|v|} in (0,1]
    return fmaxf(v, 0.f) + 0.69314718f * fast_log2(1.f + t);
}

// ---------------------------------------------------------------- pre-passes

// input (BATCH x 5000 f32) -> A16 (BATCH x 5024 f16, zero-padded K)
__global__ void cast_input_kernel(const float* __restrict__ in, f16* __restrict__ out) {
    int tid = blockIdx.x * 256 + threadIdx.x;          // one thread per 8 cols
    int r = tid / (KPAD_IN / 8);
    int k = (tid - r * (KPAD_IN / 8)) << 3;
    if (r >= BATCH) return;
    f16x8 v;
#pragma unroll
    for (int j = 0; j < 8; j++) {
        int kk = k + j;
        float x = (kk < INF) ? in[(size_t)r * INF + kk] : 0.f;
        v[j] = (f16)x;
    }
    *(f16x8*)(out + (size_t)r * KPAD_IN + k) = v;
}

// W (K x Nsrc f32, row-major) -> Wt (Ndst x Kpad f16), zero pad both dims
__global__ void tcast_kernel(const float* __restrict__ W, f16* __restrict__ Wt,
                             int K, int Nsrc, int Kpad, int Ndst) {
    int tid = blockIdx.x * 256 + threadIdx.x;
    int kb = Kpad >> 3;
    int n = tid / kb;
    int k = (tid - n * kb) << 3;
    if (n >= Ndst) return;
    f16x8 v;
#pragma unroll
    for (int j = 0; j < 8; j++) {
        int kk = k + j;
        float x = (kk < K && n < Nsrc) ? W[(size_t)kk * Nsrc + n] : 0.f;
        v[j] = (f16)x;
    }
    *(f16x8*)(Wt + (size_t)n * Kpad + k) = v;
}

// expert_w (16 x 257 x 256 f32) -> Wt (16 x 256 x 288 f16)
__global__ void tcast_expert_kernel(const float* __restrict__ W, f16* __restrict__ Wt) {
    int tid = blockIdx.x * 256 + threadIdx.x;          // 4096 n_total * 36 kblk
    int nt = tid / (XK / 8);
    int k = (tid - nt * (XK / 8)) << 3;
    if (nt >= NUM_T * N2) return;
    int t = nt >> 8, n = nt & 255;
    f16x8 v;
#pragma unroll
    for (int j = 0; j < 8; j++) {
        int kk = k + j;
        float x = (kk < N2 + 1) ? W[((size_t)t * (N2 + 1) + kk) * N2 + n] : 0.f;
        v[j] = (f16)x;
    }
    *(f16x8*)(Wt + ((size_t)t * N2 + n) * XK + k) = v;
}

// per-row argmax (first-index tiebreak) + dose; also fill x-buffer cols 256..287
__global__ void treat_kernel(const float* __restrict__ td, int* __restrict__ treat,
                             f16* __restrict__ xbuf) {
    int b = blockIdx.x * 256 + threadIdx.x;
    if (b >= BATCH) return;
    const float* row = td + (size_t)b * NUM_T;
    float mx = row[0]; int mi = 0;
#pragma unroll
    for (int i = 1; i < NUM_T; i++) {
        float v = row[i];
        if (v > mx) { mx = v; mi = i; }   // strict > keeps first occurrence
    }
    treat[b] = mi;
    f16* xr = xbuf + (size_t)b * XK;
    xr[256] = (f16)mx;                    // dose = value at argmax
#pragma unroll
    for (int i = 257; i < XK; i++) xr[i] = (f16)0.f;
}

// ---------------------------------------------------------------- GEMM

enum { EPI_F16 = 0, EPI_EXPERT = 1, EPI_DEC3 = 2 };

// C(128x128) = A(128xK) * Bt(128 rows x K)^T ; 16x16x32 f16 MFMA, fp32 acc.
// A row-major stride K (padded, %32==0); Bt row-major stride K (B pre-transposed).
template <int EPI>
__global__ __launch_bounds__(256, 2)
void gemm_tpl(const f16* __restrict__ A, const f16* __restrict__ Bt,
              const float* __restrict__ bias, int K,
              f16* __restrict__ out16, int ldo,
              const int* __restrict__ treat, float* __restrict__ outf) {
    __shared__ f16 sA[128 * 32];
    __shared__ f16 sB[128 * 32];
    const int tid  = threadIdx.x;
    const int w    = tid >> 6;
    const int lane = tid & 63;
    const int lr   = lane >> 2;          // staging: row within 16-row chunk
    const int lc8  = (lane & 3) * 8;     // staging: element offset (8 f16 = 16B)
    const int r0   = blockIdx.x * 128;
    const int n0   = blockIdx.y * 128;
    const int expert = (EPI == EPI_EXPERT) ? (int)blockIdx.z : 0;

    const f16* btBase = Bt;
    if (EPI == EPI_EXPERT) btBase += (size_t)expert * N2 * K;

    const f16* a0 = A      + (size_t)(r0 + w * 16 + lr) * K + lc8;
    const f16* a1 = a0 + (size_t)64 * K;
    const f16* b0 = btBase + (size_t)(n0 + w * 16 + lr) * K + lc8;
    const f16* b1 = b0 + (size_t)64 * K;
    f16* sA0 = sA + w * 512;             // chunk w      (1 KiB per wave-chunk)
    f16* sA1 = sA + (w + 4) * 512;       // chunk w+4
    f16* sB0 = sB + w * 512;
    f16* sB1 = sB + (w + 4) * 512;

    f32x4 acc[4][4];
#pragma unroll
    for (int i = 0; i < 4; i++)
#pragma unroll
        for (int j = 0; j < 4; j++) acc[i][j] = (f32x4){0.f, 0.f, 0.f, 0.f};

    const int wr = (w >> 1) * 64;        // wave's 64x64 quadrant
    const int wc = (w & 1) * 64;
    const int fm = lane & 15;            // frag row (A) / frag col-row (B)
    const int fk = (lane >> 4) * 8;      // frag k offset

    for (int k0 = 0; k0 < K; k0 += 32) {
        __syncthreads();                 // LDS safe to overwrite
        gload_lds16(a0, sA0); gload_lds16(a1, sA1);
        gload_lds16(b0, sB0); gload_lds16(b1, sB1);
        a0 += 32; a1 += 32; b0 += 32; b1 += 32;
        __syncthreads();                 // drains vmcnt -> tiles visible

        f16x8 af[4], bf[4];
#pragma unroll
        for (int mi = 0; mi < 4; mi++)
            af[mi] = *(const f16x8*)(sA + (wr + mi * 16 + fm) * 32 + fk);
#pragma unroll
        for (int ni = 0; ni < 4; ni++)
            bf[ni] = *(const f16x8*)(sB + (wc + ni * 16 + fm) * 32 + fk);
#pragma unroll
        for (int mi = 0; mi < 4; mi++)
#pragma unroll
            for (int ni = 0; ni < 4; ni++)
                acc[mi][ni] = __builtin_amdgcn_mfma_f32_16x16x32_f16(
                    af[mi], bf[ni], acc[mi][ni], 0, 0, 0);
    }

    // epilogue: C/D layout row=(lane>>4)*4+reg, col=lane&15
    const float* bp = (EPI == EPI_EXPERT) ? bias + expert * N2 : bias;
    const int rbase = r0 + wr + ((lane >> 4) << 2);
    const int cbase = n0 + wc + fm;
#pragma unroll
    for (int mi = 0; mi < 4; mi++) {
#pragma unroll
        for (int r = 0; r < 4; r++) {
            int row = rbase + mi * 16 + r;
            if (EPI == EPI_EXPERT) {
                if (treat[row] != expert) continue;
            }
#pragma unroll
            for (int ni = 0; ni < 4; ni++) {
                int col = cbase + ni * 16;
                float v = acc[mi][ni][r] + bp[col];
                if (EPI == EPI_F16) {
                    out16[(size_t)row * ldo + col] = (f16)fmaxf(v, 0.f);
                } else if (EPI == EPI_EXPERT) {
                    v = fmaxf(v, 0.f);
                    out16[(size_t)row * N2 + col] = (f16)v;   // fp16 for dec1
                    outf[(size_t)row * N2 + col] = v;         // latent_rep out
                } else { // EPI_DEC3
                    if (col < N3) {
                        if (col >= INF)  // softplus(v)+1e-3 for variance half
                            v = fast_softplus(v) + 0.001f;
                        outf[(size_t)row * N3 + col] = v;
                    }
                }
            }
        }
    }
}

// ---------------------------------------------------------------- launcher

extern "C" void kernel_launch(void* const* d_in, const int* in_sizes, int n_in,
                              void* d_out, int out_size, void* d_ws, size_t ws_size,
                              hipStream_t stream) {
    const float* in_x  = (const float*)d_in[0];
    const float* td    = (const float*)d_in[1];
    const float* ew1   = (const float*)d_in[2];
    const float* eb1   = (const float*)d_in[3];
    const float* ew2   = (const float*)d_in[4];
    const float* eb2   = (const float*)d_in[5];
    const float* exw   = (const float*)d_in[6];
    const float* exb   = (const float*)d_in[7];
    const float* dw1   = (const float*)d_in[8];
    const float* db1   = (const float*)d_in[9];
    const float* dw2   = (const float*)d_in[10];
    const float* db2   = (const float*)d_in[11];
    const float* dw3   = (const float*)d_in[12];
    const float* db3   = (const float*)d_in[13];
    float* out = (float*)d_out;
    float* out_latent = out + (size_t)BATCH * N3;

    // workspace carve-up (256B aligned)
    size_t off = 0;
    auto carve = [&](size_t bytes) {
        size_t p = off;
        off += (bytes + 255) & ~(size_t)255;
        return p;
    };
    char* ws = (char*)d_ws;
    f16* A16   = (f16*)(ws + carve((size_t)BATCH * KPAD_IN * 2));
    f16* h1    = (f16*)(ws + carve((size_t)BATCH * N0 * 2));
    f16* xbuf  = (f16*)(ws + carve((size_t)BATCH * XK * 2));
    f16* lat16 = (f16*)(ws + carve((size_t)BATCH * N2 * 2));
    f16* d1    = (f16*)(ws + carve((size_t)BATCH * N1 * 2));
    f16* d2    = (f16*)(ws + carve((size_t)BATCH * N0 * 2));
    f16* w1t   = (f16*)(ws + carve((size_t)N0 * KPAD_IN * 2));
    f16* w2t   = (f16*)(ws + carve((size_t)N2 * 512 * 2));
    f16* wet   = (f16*)(ws + carve((size_t)NUM_T * N2 * XK * 2));
    f16* wd1t  = (f16*)(ws + carve((size_t)N1 * 256 * 2));
    f16* wd2t  = (f16*)(ws + carve((size_t)N0 * 512 * 2));
    f16* wd3t  = (f16*)(ws + carve((size_t)N3PAD * 512 * 2));
    int* treat = (int*)(ws + carve((size_t)BATCH * 4));
    (void)ws_size; (void)in_sizes; (void)n_in; (void)out_size;

    auto blocks = [](size_t threads) { return (unsigned)((threads + 255) / 256); };

    // pre-passes
    cast_input_kernel<<<blocks((size_t)BATCH * (KPAD_IN / 8)), 256, 0, stream>>>(in_x, A16);
    tcast_kernel<<<blocks((size_t)N0 * (KPAD_IN / 8)), 256, 0, stream>>>(ew1, w1t, INF, N0, KPAD_IN, N0);
    tcast_kernel<<<blocks((size_t)N2 * (512 / 8)), 256, 0, stream>>>(ew2, w2t, N0, N2, 512, N2);
    tcast_expert_kernel<<<blocks((size_t)NUM_T * N2 * (XK / 8)), 256, 0, stream>>>(exw, wet);
    tcast_kernel<<<blocks((size_t)N1 * (256 / 8)), 256, 0, stream>>>(dw1, wd1t, N2, N1, 256, N1);
    tcast_kernel<<<blocks((size_t)N0 * (512 / 8)), 256, 0, stream>>>(dw2, wd2t, N1, N0, 512, N0);
    tcast_kernel<<<blocks((size_t)N3PAD * (512 / 8)), 256, 0, stream>>>(dw3, wd3t, N0, N3, 512, N3PAD);
    treat_kernel<<<blocks(BATCH), 256, 0, stream>>>(td, treat, xbuf);

    // h1 = relu(input @ enc_w1 + b1)            M=16384 N=512 K=5024
    gemm_tpl<EPI_F16><<<dim3(BATCH / 128, N0 / 128, 1), 256, 0, stream>>>(
        A16, w1t, eb1, KPAD_IN, h1, N0, nullptr, nullptr);
    // emb = relu(h1 @ enc_w2 + b2) -> xbuf[:, 0:256]   N=256 K=512
    gemm_tpl<EPI_F16><<<dim3(BATCH / 128, N2 / 128, 1), 256, 0, stream>>>(
        h1, w2t, eb2, 512, xbuf, XK, nullptr, nullptr);
    // latent = relu(x @ expert_w[t] + expert_b[t]) (dense over 16, masked write)
    gemm_tpl<EPI_EXPERT><<<dim3(BATCH / 128, N2 / 128, NUM_T), 256, 0, stream>>>(
        xbuf, wet, exb, XK, lat16, N2, treat, out_latent);
    // d1 = relu(latent @ dec_w1 + b1)           N=512 K=256
    gemm_tpl<EPI_F16><<<dim3(BATCH / 128, N1 / 128, 1), 256, 0, stream>>>(
        lat16, wd1t, db1, 256, d1, N1, nullptr, nullptr);
    // d2 = relu(d1 @ dec_w2 + b2)               N=512 K=512
    gemm_tpl<EPI_F16><<<dim3(BATCH / 128, N0 / 128, 1), 256, 0, stream>>>(
        d1, wd2t, db2, 512, d2, N0, nullptr, nullptr);
    // rec = d2 @ dec_w3 + b3 ; means | softplus+1e-3   N=10112(pad) K=512
    gemm_tpl<EPI_DEC3><<<dim3(BATCH / 128, N3PAD / 128, 1), 256, 0, stream>>>(
        d2, wd3t, db3, 512, nullptr, 0, nullptr, out);
}

// Round 2
// 1505.444 us; speedup vs baseline: 1.1433x; 1.0354x over previous
//
#include <hip/hip_runtime.h>
#include <cstdint>
#include <cstddef>

#define BATCH    16384
#define INF      5000
#define KPAD_IN  5024      // 157*32
#define N0       512
#define N1       512
#define N2       256
#define NUM_T    16
#define XK       288       // 257 padded to 9*32
#define N3       10000
#define N3PAD    10112     // 79*128

typedef _Float16 f16;
typedef _Float16 f16x8 __attribute__((ext_vector_type(8)));
typedef float    f32x4 __attribute__((ext_vector_type(4)));
typedef float    float4v __attribute__((ext_vector_type(4)));

typedef __attribute__((address_space(1))) void gvoid;
typedef __attribute__((address_space(3))) void lvoid;

__device__ __forceinline__ void gload_lds16(const void* g, void* l) {
    // async global->LDS, 16B/lane; LDS dest = wave-uniform base + lane*16
    __builtin_amdgcn_global_load_lds((gvoid*)g, (lvoid*)l, 16, 0, 0);
}

// hardware transcendentals: v_exp_f32 = 2^x, v_log_f32 = log2(x)
__device__ __forceinline__ float fast_exp2(float x) {
    float r; asm("v_exp_f32 %0, %1" : "=v"(r) : "v"(x)); return r;
}
__device__ __forceinline__ float fast_log2(float x) {
    float r; asm("v_log_f32 %0, %1" : "=v"(r) : "v"(x)); return r;
}
// softplus(v) = max(v,0) + ln2*log2(1 + 2^(-|v|*log2e)); stable, ~9 VALU ops
__device__ __forceinline__ float fast_softplus(float v) {
    float t = fast_exp2(-fabsf(v) * 1.44269504f);      // e^{-|v|} in (0,1]
    return fmaxf(v, 0.f) + 0.69314718f * fast_log2(1.f + t);
}

// ---------------------------------------------------------------- pre-passes

// input (BATCH x 5000 f32) -> A16 (BATCH x 5024 f16, zero-padded K)
__global__ void cast_input_kernel(const float* __restrict__ in, f16* __restrict__ out) {
    int tid = blockIdx.x * 256 + threadIdx.x;          // one thread per 8 cols
    int r = tid / (KPAD_IN / 8);
    int k = (tid - r * (KPAD_IN / 8)) << 3;
    if (r >= BATCH) return;
    f16x8 v;
    if (k + 8 <= INF) {                  // vector fast path: 2x float4
        float4v x0 = *(const float4v*)(in + (size_t)r * INF + k);
        float4v x1 = *(const float4v*)(in + (size_t)r * INF + k + 4);
#pragma unroll
        for (int j = 0; j < 4; j++) { v[j] = (f16)x0[j]; v[j + 4] = (f16)x1[j]; }
    } else {
#pragma unroll
        for (int j = 0; j < 8; j++) {
            int kk = k + j;
            float x = (kk < INF) ? in[(size_t)r * INF + kk] : 0.f;
            v[j] = (f16)x;
        }
    }
    *(f16x8*)(out + (size_t)r * KPAD_IN + k) = v;
}

// W (K x Nsrc f32, row-major) -> Wt (Ndst x Kpad f16), zero pad both dims
__global__ void tcast_kernel(const float* __restrict__ W, f16* __restrict__ Wt,
                             int K, int Nsrc, int Kpad, int Ndst) {
    int tid = blockIdx.x * 256 + threadIdx.x;
    int kb = Kpad >> 3;
    int n = tid / kb;
    int k = (tid - n * kb) << 3;
    if (n >= Ndst) return;
    f16x8 v;
#pragma unroll
    for (int j = 0; j < 8; j++) {
        int kk = k + j;
        float x = (kk < K && n < Nsrc) ? W[(size_t)kk * Nsrc + n] : 0.f;
        v[j] = (f16)x;
    }
    *(f16x8*)(Wt + (size_t)n * Kpad + k) = v;
}

// expert_w (16 x 257 x 256 f32) -> Wt (16 x 256 x 288 f16)
__global__ void tcast_expert_kernel(const float* __restrict__ W, f16* __restrict__ Wt) {
    int tid = blockIdx.x * 256 + threadIdx.x;          // 4096 n_total * 36 kblk
    int nt = tid / (XK / 8);
    int k = (tid - nt * (XK / 8)) << 3;
    if (nt >= NUM_T * N2) return;
    int t = nt >> 8, n = nt & 255;
    f16x8 v;
#pragma unroll
    for (int j = 0; j < 8; j++) {
        int kk = k + j;
        float x = (kk < N2 + 1) ? W[((size_t)t * (N2 + 1) + kk) * N2 + n] : 0.f;
        v[j] = (f16)x;
    }
    *(f16x8*)(Wt + ((size_t)t * N2 + n) * XK + k) = v;
}

// per-row argmax (first-index tiebreak) + dose; also fill x-buffer cols 256..287
__global__ void treat_kernel(const float* __restrict__ td, int* __restrict__ treat,
                             f16* __restrict__ xbuf) {
    int b = blockIdx.x * 256 + threadIdx.x;
    if (b >= BATCH) return;
    const float* row = td + (size_t)b * NUM_T;
    float mx = row[0]; int mi = 0;
#pragma unroll
    for (int i = 1; i < NUM_T; i++) {
        float v = row[i];
        if (v > mx) { mx = v; mi = i; }   // strict > keeps first occurrence
    }
    treat[b] = mi;
    f16* xr = xbuf + (size_t)b * XK;
    xr[256] = (f16)mx;                    // dose = value at argmax
#pragma unroll
    for (int i = 257; i < XK; i++) xr[i] = (f16)0.f;
}

// ---------------------------------------------------------------- GEMM

enum { EPI_F16 = 0, EPI_EXPERT = 1, EPI_DEC3 = 2 };

// C(128x128) = A(128xK) * Bt(128 rows x K)^T ; 16x16x32 f16 MFMA, fp32 acc.
// A row-major stride K (padded, %32==0); Bt row-major stride K (B pre-transposed).
// 2-phase double-buffered K-loop (T3-minimum): stage t+1 before computing t,
// one __syncthreads per K-step (its implicit vmcnt(0) drain lands AFTER the
// MFMA work, so the global->LDS latency overlaps compute).
// LDS bank-conflict swizzle (both-sides, rule #21): 16B slot within each 64B
// row is XOR'd with (row&3) at the GLOBAL source during staging (LDS dest of
// global_load_lds must stay linear) and the same XOR applied on ds_read.
template <int EPI>
__global__ __launch_bounds__(256, 4)
void gemm_tpl(const f16* __restrict__ A, const f16* __restrict__ Bt,
              const float* __restrict__ bias, int K,
              f16* __restrict__ out16, int ldo,
              const int* __restrict__ treat, float* __restrict__ outf) {
    __shared__ f16 sA[2][128 * 32];
    __shared__ f16 sB[2][128 * 32];
    const int tid  = threadIdx.x;
    const int w    = tid >> 6;
    const int lane = tid & 63;
    const int lr   = lane >> 2;          // staging: row within 16-row chunk
    // staging: swizzled source slot (8 f16 = 16B units)
    const int lc8  = (((lane & 3) ^ (lr & 3)) << 3);
    const int r0   = blockIdx.x * 128;
    const int n0   = blockIdx.y * 128;
    const int expert = (EPI == EPI_EXPERT) ? (int)blockIdx.z : 0;

    const f16* btBase = Bt;
    if (EPI == EPI_EXPERT) btBase += (size_t)expert * N2 * K;

    const f16* a0 = A      + (size_t)(r0 + w * 16 + lr) * K + lc8;
    const f16* a1 = a0 + (size_t)64 * K;
    const f16* b0 = btBase + (size_t)(n0 + w * 16 + lr) * K + lc8;
    const f16* b1 = b0 + (size_t)64 * K;
    const int so = w * 512;              // wave's chunk base (f16 units)

    f32x4 acc[4][4];
#pragma unroll
    for (int i = 0; i < 4; i++)
#pragma unroll
        for (int j = 0; j < 4; j++) acc[i][j] = (f32x4){0.f, 0.f, 0.f, 0.f};

    const int wr = (w >> 1) * 64;        // wave's 64x64 quadrant
    const int wc = (w & 1) * 64;
    const int fm = lane & 15;            // frag row (A) / frag col-row (B)
    // read: swizzled slot, loop-invariant: slot = (k-slot) ^ (row&3), row&3==lane&3
    const int fk = (((lane >> 4) ^ (lane & 3)) << 3);

    auto stage = [&](int buf) {
        f16* bA = &sA[buf][0];
        f16* bB = &sB[buf][0];
        gload_lds16(a0, bA + so); gload_lds16(a1, bA + so + 2048);
        gload_lds16(b0, bB + so); gload_lds16(b1, bB + so + 2048);
        a0 += 32; a1 += 32; b0 += 32; b1 += 32;
    };
    auto compute = [&](int buf) {
        const f16* pA = &sA[buf][0];
        const f16* pB = &sB[buf][0];
        f16x8 af[4], bf[4];
#pragma unroll
        for (int mi = 0; mi < 4; mi++)
            af[mi] = *(const f16x8*)(pA + (wr + mi * 16 + fm) * 32 + fk);
#pragma unroll
        for (int ni = 0; ni < 4; ni++)
            bf[ni] = *(const f16x8*)(pB + (wc + ni * 16 + fm) * 32 + fk);
#pragma unroll
        for (int mi = 0; mi < 4; mi++)
#pragma unroll
            for (int ni = 0; ni < 4; ni++)
                acc[mi][ni] = __builtin_amdgcn_mfma_f32_16x16x32_f16(
                    af[mi], bf[ni], acc[mi][ni], 0, 0, 0);
    };

    const int nt = K >> 5;
    stage(0);
    __syncthreads();                     // buf0 resident
    int t = 0;
    while (t + 2 <= nt) {
        stage(1);                        // prefetch iter t+1
        compute(0);                      // compute iter t
        __syncthreads();                 // drain: buf1 resident, buf0 reusable
        if (t + 2 < nt) stage(0);        // prefetch iter t+2
        compute(1);                      // compute iter t+1
        __syncthreads();
        t += 2;
    }
    if (t < nt) compute(0);              // odd tail (already staged)

    // epilogue: C/D layout row=(lane>>4)*4+reg, col=lane&15
    const float* bp = (EPI == EPI_EXPERT) ? bias + expert * N2 : bias;
    const int rbase = r0 + wr + ((lane >> 4) << 2);
    const int cbase = n0 + wc + fm;
#pragma unroll
    for (int mi = 0; mi < 4; mi++) {
#pragma unroll
        for (int r = 0; r < 4; r++) {
            int row = rbase + mi * 16 + r;
            if (EPI == EPI_EXPERT) {
                if (treat[row] != expert) continue;
            }
#pragma unroll
            for (int ni = 0; ni < 4; ni++) {
                int col = cbase + ni * 16;
                float v = acc[mi][ni][r] + bp[col];
                if (EPI == EPI_F16) {
                    out16[(size_t)row * ldo + col] = (f16)fmaxf(v, 0.f);
                } else if (EPI == EPI_EXPERT) {
                    v = fmaxf(v, 0.f);
                    out16[(size_t)row * N2 + col] = (f16)v;   // fp16 for dec1
                    outf[(size_t)row * N2 + col] = v;         // latent_rep out
                } else { // EPI_DEC3
                    if (col < N3) {
                        if (col >= INF)  // softplus(v)+1e-3 for variance half
                            v = fast_softplus(v) + 0.001f;
                        outf[(size_t)row * N3 + col] = v;
                    }
                }
            }
        }
    }
}

// ---------------------------------------------------------------- launcher

extern "C" void kernel_launch(void* const* d_in, const int* in_sizes, int n_in,
                              void* d_out, int out_size, void* d_ws, size_t ws_size,
                              hipStream_t stream) {
    const float* in_x  = (const float*)d_in[0];
    const float* td    = (const float*)d_in[1];
    const float* ew1   = (const float*)d_in[2];
    const float* eb1   = (const float*)d_in[3];
    const float* ew2   = (const float*)d_in[4];
    const float* eb2   = (const float*)d_in[5];
    const float* exw   = (const float*)d_in[6];
    const float* exb   = (const float*)d_in[7];
    const float* dw1   = (const float*)d_in[8];
    const float* db1   = (const float*)d_in[9];
    const float* dw2   = (const float*)d_in[10];
    const float* db2   = (const float*)d_in[11];
    const float* dw3   = (const float*)d_in[12];
    const float* db3   = (const float*)d_in[13];
    float* out = (float*)d_out;
    float* out_latent = out + (size_t)BATCH * N3;

    // workspace carve-up (256B aligned)
    size_t off = 0;
    auto carve = [&](size_t bytes) {
        size_t p = off;
        off += (bytes + 255) & ~(size_t)255;
        return p;
    };
    char* ws = (char*)d_ws;
    f16* A16   = (f16*)(ws + carve((size_t)BATCH * KPAD_IN * 2));
    f16* h1    = (f16*)(ws + carve((size_t)BATCH * N0 * 2));
    f16* xbuf  = (f16*)(ws + carve((size_t)BATCH * XK * 2));
    f16* lat16 = (f16*)(ws + carve((size_t)BATCH * N2 * 2));
    f16* d1    = (f16*)(ws + carve((size_t)BATCH * N1 * 2));
    f16* d2    = (f16*)(ws + carve((size_t)BATCH * N0 * 2));
    f16* w1t   = (f16*)(ws + carve((size_t)N0 * KPAD_IN * 2));
    f16* w2t   = (f16*)(ws + carve((size_t)N2 * 512 * 2));
    f16* wet   = (f16*)(ws + carve((size_t)NUM_T * N2 * XK * 2));
    f16* wd1t  = (f16*)(ws + carve((size_t)N1 * 256 * 2));
    f16* wd2t  = (f16*)(ws + carve((size_t)N0 * 512 * 2));
    f16* wd3t  = (f16*)(ws + carve((size_t)N3PAD * 512 * 2));
    int* treat = (int*)(ws + carve((size_t)BATCH * 4));
    (void)ws_size; (void)in_sizes; (void)n_in; (void)out_size;

    auto blocks = [](size_t threads) { return (unsigned)((threads + 255) / 256); };

    // pre-passes
    cast_input_kernel<<<blocks((size_t)BATCH * (KPAD_IN / 8)), 256, 0, stream>>>(in_x, A16);
    tcast_kernel<<<blocks((size_t)N0 * (KPAD_IN / 8)), 256, 0, stream>>>(ew1, w1t, INF, N0, KPAD_IN, N0);
    tcast_kernel<<<blocks((size_t)N2 * (512 / 8)), 256, 0, stream>>>(ew2, w2t, N0, N2, 512, N2);
    tcast_expert_kernel<<<blocks((size_t)NUM_T * N2 * (XK / 8)), 256, 0, stream>>>(exw, wet);
    tcast_kernel<<<blocks((size_t)N1 * (256 / 8)), 256, 0, stream>>>(dw1, wd1t, N2, N1, 256, N1);
    tcast_kernel<<<blocks((size_t)N0 * (512 / 8)), 256, 0, stream>>>(dw2, wd2t, N1, N0, 512, N0);
    tcast_kernel<<<blocks((size_t)N3PAD * (512 / 8)), 256, 0, stream>>>(dw3, wd3t, N0, N3, 512, N3PAD);
    treat_kernel<<<blocks(BATCH), 256, 0, stream>>>(td, treat, xbuf);

    // h1 = relu(input @ enc_w1 + b1)            M=16384 N=512 K=5024
    gemm_tpl<EPI_F16><<<dim3(BATCH / 128, N0 / 128, 1), 256, 0, stream>>>(
        A16, w1t, eb1, KPAD_IN, h1, N0, nullptr, nullptr);
    // emb = relu(h1 @ enc_w2 + b2) -> xbuf[:, 0:256]   N=256 K=512
    gemm_tpl<EPI_F16><<<dim3(BATCH / 128, N2 / 128, 1), 256, 0, stream>>>(
        h1, w2t, eb2, 512, xbuf, XK, nullptr, nullptr);
    // latent = relu(x @ expert_w[t] + expert_b[t]) (dense over 16, masked write)
    gemm_tpl<EPI_EXPERT><<<dim3(BATCH / 128, N2 / 128, NUM_T), 256, 0, stream>>>(
        xbuf, wet, exb, XK, lat16, N2, treat, out_latent);
    // d1 = relu(latent @ dec_w1 + b1)           N=512 K=256
    gemm_tpl<EPI_F16><<<dim3(BATCH / 128, N1 / 128, 1), 256, 0, stream>>>(
        lat16, wd1t, db1, 256, d1, N1, nullptr, nullptr);
    // d2 = relu(d1 @ dec_w2 + b2)               N=512 K=512
    gemm_tpl<EPI_F16><<<dim3(BATCH / 128, N0 / 128, 1), 256, 0, stream>>>(
        d1, wd2t, db2, 512, d2, N0, nullptr, nullptr);
    // rec = d2 @ dec_w3 + b3 ; means | softplus+1e-3   N=10112(pad) K=512
    gemm_tpl<EPI_DEC3><<<dim3(BATCH / 128, N3PAD / 128, 1), 256, 0, stream>>>(
        d2, wd3t, db3, 512, nullptr, 0, nullptr, out);
}